// Round 7
// baseline (323.505 us; speedup 1.0000x reference)
//
#include <hip/hip_runtime.h>
#include <cmath>

#define B_ 512
#define EPS_ 1e-8f

typedef __bf16 bf16x8 __attribute__((ext_vector_type(8)));
typedef float f32x4 __attribute__((ext_vector_type(4)));
typedef unsigned uint32x4_ __attribute__((ext_vector_type(4)));

__device__ __forceinline__ float sigmoidf_(float x) { return 1.f / (1.f + expf(-x)); }
__device__ __forceinline__ float softplusf_(float x) { return x > 20.f ? x : log1pf(expf(x)); }
__device__ __forceinline__ unsigned f2bf(float x) {
  union { float f; unsigned u; } v; v.f = x;
  unsigned r = v.u + 0x7FFF + ((v.u >> 16) & 1);
  return r >> 16;
}
__device__ __forceinline__ float bfhi2f(unsigned u) { return __uint_as_float(u & 0xffff0000u); }
__device__ __forceinline__ float bflo2f(unsigned u) { return __uint_as_float(u << 16); }
// packed f32->bf16 (RNE), lo = a, hi = b
__device__ __forceinline__ unsigned cvtpk(float a, float b) {
  unsigned r;
  asm("v_cvt_pk_bf16_f32 %0, %1, %2" : "=v"(r) : "v"(a), "v"(b));
  return r;
}

// ---------------- one prep kernel: x2b + all weight conversions (grid-stride)
__global__ void k_prep(const float* __restrict__ in_data, const float* __restrict__ prev_reads,
                       const float* __restrict__ h0,
                       const float* __restrict__ W_ih, const float* __restrict__ W_hh,
                       const float* __restrict__ b_ih, const float* __restrict__ b_hh,
                       const float* __restrict__ W_rh, const float* __restrict__ W_wh,
                       const float* __restrict__ W_out,
                       const float* __restrict__ b_rh, const float* __restrict__ b_wh,
                       unsigned short* __restrict__ x2b,
                       unsigned short* __restrict__ Wcatb, float* __restrict__ bcat,
                       unsigned short* __restrict__ W2b, unsigned short* __restrict__ Woutb,
                       float* __restrict__ bcat2) {
  const int stride = gridDim.x * blockDim.x;
  const int t0 = blockIdx.x * blockDim.x + threadIdx.x;
  for (int i = t0; i < 512 * 1024; i += stride) {
    const int b = i >> 10, j = i & 1023;
    float v;
    if (j < 256) v = in_data[(size_t)b * 256 + j];
    else if (j < 512) { const int jj = j - 256; v = prev_reads[(size_t)(jj >> 6) * B_ * 64 + (size_t)b * 64 + (jj & 63)]; }
    else v = h0[(size_t)b * 512 + (j - 512)];
    x2b[i] = (unsigned short)f2bf(v);
  }
  for (int i = t0; i < 2048 * 1024; i += stride) {
    const int j = i >> 10, k = i & 1023;
    Wcatb[i] = (unsigned short)f2bf(k < 512 ? W_ih[(size_t)j * 512 + k] : W_hh[(size_t)j * 512 + (k - 512)]);
  }
  for (int i = t0; i < 2048; i += stride) bcat[i] = b_ih[i] + b_hh[i];
  for (int i = t0; i < 143360; i += stride) W2b[i] = (unsigned short)f2bf(W_rh[i]);
  for (int i = t0; i < 405504; i += stride) W2b[143360 + i] = (unsigned short)f2bf(W_wh[i]);
  for (int i = t0; i < 196608; i += stride) Woutb[i] = (unsigned short)f2bf(W_out[i]);
  for (int i = t0; i < 280; i += stride) bcat2[i] = b_rh[i];
  for (int i = t0; i < 792; i += stride) bcat2[280 + i] = b_wh[i];
}

// ---------------- bf16 MFMA GEMM, one wave per 32x32 tile, direct-from-global frags
template <bool SIG>
__global__ __launch_bounds__(64) void k_gemm_mfma(const unsigned short* __restrict__ A, int lda,
                                                  const unsigned short* __restrict__ W,
                                                  const float* __restrict__ bias,
                                                  float* __restrict__ C,
                                                  int Nn, int Kk, int ldc) {
  const int l = threadIdx.x;
  const int m0 = blockIdx.y * 32, n0 = blockIdx.x * 32;
  const int lr = l & 15, lk = (l >> 4) * 8;
  f32x4 acc00 = {0.f, 0.f, 0.f, 0.f}, acc01 = acc00, acc10 = acc00, acc11 = acc00;
  const size_t pa0 = (size_t)(m0 + lr) * lda + lk;
  const size_t pa1 = pa0 + (size_t)16 * lda;
  const bool bok0 = (n0 + lr) < Nn, bok1 = (n0 + 16 + lr) < Nn;
  const size_t pb0 = (size_t)(n0 + lr) * Kk + lk;
  const size_t pb1 = pb0 + (size_t)16 * Kk;
#pragma unroll 4
  for (int k0 = 0; k0 < Kk; k0 += 32) {
    bf16x8 a0 = *(const bf16x8*)(A + pa0 + k0);
    bf16x8 a1 = *(const bf16x8*)(A + pa1 + k0);
    bf16x8 b0 = {}, b1 = {};
    if (bok0) b0 = *(const bf16x8*)(W + pb0 + k0);
    if (bok1) b1 = *(const bf16x8*)(W + pb1 + k0);
    acc00 = __builtin_amdgcn_mfma_f32_16x16x32_bf16(a0, b0, acc00, 0, 0, 0);
    acc01 = __builtin_amdgcn_mfma_f32_16x16x32_bf16(a0, b1, acc01, 0, 0, 0);
    acc10 = __builtin_amdgcn_mfma_f32_16x16x32_bf16(a1, b0, acc10, 0, 0, 0);
    acc11 = __builtin_amdgcn_mfma_f32_16x16x32_bf16(a1, b1, acc11, 0, 0, 0);
  }
  const int orow = (l >> 4) * 4;
  f32x4 accs[2][2] = {{acc00, acc01}, {acc10, acc11}};
#pragma unroll
  for (int mi = 0; mi < 2; ++mi) {
#pragma unroll
    for (int nj = 0; nj < 2; ++nj) {
      const int n = n0 + nj * 16 + lr;
      if (n < Nn) {
        const float bv = bias[n];
#pragma unroll
        for (int r = 0; r < 4; ++r) {
          const int m = m0 + mi * 16 + orow + r;
          float v = accs[mi][nj][r] + bv;
          if (SIG) v = 1.f / (1.f + expf(-v));
          C[(size_t)m * ldc + n] = v;
        }
      }
    }
  }
}

// ---------------- LSTM pointwise -> h (bf16) into Aoutb rows (stride 768)
__global__ void k_lstm(const float* __restrict__ gates, const float* __restrict__ c0,
                       unsigned short* __restrict__ Aoutb) {
  const int idx = blockIdx.x * blockDim.x + threadIdx.x;  // < 512*512
  const int b = idx >> 9, j = idx & 511;
  const float* g = gates + (size_t)b * 2048;
  const float ig = g[j], fg = g[512 + j], gg = g[1024 + j], og = g[1536 + j];
  const float c = sigmoidf_(fg) * c0[idx] + sigmoidf_(ig) * tanhf(gg);
  Aoutb[(size_t)b * 768 + j] = (unsigned short)f2bf(sigmoidf_(og) * tanhf(c));
}

// ---------------- fused NTM head loop: one 512-thread block per batch row.
// Memory image lives in REGISTERS in MFMA A-frag layout (8 tiles/wave, 2 frags):
// lane holds row = tile*16 + (l&15), cols (l>>4)*8.. (a) and 32+(l>>4)*8.. (b).
// Scores/norms via MFMA from regs; update in-register; reads via per-lane fma
// partials + 15-shuffle fold. LDS only for weights/softmax (~19 KB) -> 2 blk/CU.
__global__ __launch_bounds__(512, 4) void k_mega(const float* __restrict__ mem0,
                                                 const float* __restrict__ P,
                                                 const float* __restrict__ prev_w_r,
                                                 const float* __restrict__ prev_w_w,
                                                 unsigned short* __restrict__ Aoutb) {
  const int b = blockIdx.x;
  const int t = threadIdx.x;   // 512
  const int l = t & 63;
  const int w = t >> 6;        // wave 0..7
  const int p = l & 15;        // frag row within tile
  const int q = l >> 4;        // k-chunk

  __shared__ float Ar[1024], Aw[1024], nrm_s[1024];
  __shared__ float racc[8][64];
  __shared__ float knb[8][64];
  __shared__ float parb[8][8];
  __shared__ float eb[4][64], ab[4][64];
  __shared__ float redB[8], redC[8];

  // ---- stage memory rows into register fragments (f32 global -> packed bf16)
  uint32x4_ va[8], vb[8];
  {
    const float* src = mem0 + (size_t)b * 65536;
#pragma unroll
    for (int tt = 0; tt < 8; ++tt) {
      const float* rp = src + ((w * 8 + tt) * 16 + p) * 64;
      const float4 f0 = *(const float4*)(rp + q * 8);
      const float4 f1 = *(const float4*)(rp + q * 8 + 4);
      const float4 f2 = *(const float4*)(rp + 32 + q * 8);
      const float4 f3 = *(const float4*)(rp + 32 + q * 8 + 4);
      va[tt][0] = cvtpk(f0.x, f0.y); va[tt][1] = cvtpk(f0.z, f0.w);
      va[tt][2] = cvtpk(f1.x, f1.y); va[tt][3] = cvtpk(f1.z, f1.w);
      vb[tt][0] = cvtpk(f2.x, f2.y); vb[tt][1] = cvtpk(f2.z, f2.w);
      vb[tt][2] = cvtpk(f3.x, f3.y); vb[tt][3] = cvtpk(f3.z, f3.w);
    }
  }

  // ---- params phase (each wave = one unit: type = w>>2, head = w&3)
  {
    const int type = w >> 2, head = w & 3;
    const float* pp = P + (size_t)b * 1072 + (type == 0 ? head * 70 : 280 + head * 198);
    const float kv = tanhf(pp[l]);
    float ss = kv * kv;
#pragma unroll
    for (int off = 32; off > 0; off >>= 1) ss += __shfl_xor(ss, off);
    knb[w][l] = kv / (sqrtf(ss) + EPS_);
    if (l == 0) {
      parb[w][0] = softplusf_(pp[64]);
      parb[w][1] = sigmoidf_(pp[65]);
      const float s0 = pp[66], s1 = pp[67], s2 = pp[68];
      const float mx = fmaxf(s0, fmaxf(s1, s2));
      const float e0 = expf(s0 - mx), e1 = expf(s1 - mx), e2 = expf(s2 - mx);
      const float inv = 1.f / (e0 + e1 + e2);
      parb[w][2] = e0 * inv; parb[w][3] = e1 * inv; parb[w][4] = e2 * inv;
      parb[w][5] = 1.f + softplusf_(pp[69]);
    }
    if (type == 1) {
      eb[head][l] = sigmoidf_(pp[70 + l]);
      ab[head][l] = tanhf(pp[134 + l]);
    }
  }
  __syncthreads();

  // ---- key B-fragments (cols 0..3 read keys, 4..7 write keys, 8..15 zero)
  bf16x8 kb0 = {}, kb1 = {};
  {
    const int c = l & 15, ks = (l >> 4) * 8;
    if (c < 8) {
#pragma unroll
      for (int j = 0; j < 8; ++j) {
        kb0[j] = (__bf16)knb[c][ks + j];
        kb1[j] = (__bf16)knb[c][32 + ks + j];
      }
    }
  }

  // ---- MFMA score pass from registers: scores for head hj + Gram-diag norms
  auto score_pass = [&](int hj) {
#pragma unroll
    for (int tt = 0; tt < 8; ++tt) {
      const int tile = w * 8 + tt;
      const bf16x8 a0 = __builtin_bit_cast(bf16x8, va[tt]);
      const bf16x8 a1 = __builtin_bit_cast(bf16x8, vb[tt]);
      f32x4 sacc = {0.f, 0.f, 0.f, 0.f}, gacc = {0.f, 0.f, 0.f, 0.f};
      sacc = __builtin_amdgcn_mfma_f32_16x16x32_bf16(a0, kb0, sacc, 0, 0, 0);
      sacc = __builtin_amdgcn_mfma_f32_16x16x32_bf16(a1, kb1, sacc, 0, 0, 0);
      gacc = __builtin_amdgcn_mfma_f32_16x16x32_bf16(a0, a0, gacc, 0, 0, 0);
      gacc = __builtin_amdgcn_mfma_f32_16x16x32_bf16(a1, a1, gacc, 0, 0, 0);
      if (p == hj)        *(f32x4*)&Ar[tile * 16 + q * 4] = sacc;
      if (p == 4 + hj)    *(f32x4*)&Aw[tile * 16 + q * 4] = sacc;
      if ((p >> 2) == q)  nrm_s[tile * 16 + p] = gacc[p & 3];
    }
  };

  score_pass(0);
  __syncthreads();  // scores + norms ready for head 0

  const int h = w >> 2;      // 0: read-type half (waves 0-3), 1: write-type half
  const int th = t & 255;
  float* Abuf = h ? Aw : Ar;

  for (int i = 0; i < 4; ++i) {
    // ---- finalize: cosine-normalize + softmax (no max-sub; beta<=~1) + gate + shift + sharpen
    const float beta = parb[h * 4 + i][0], g = parb[h * 4 + i][1];
    const float sh0 = parb[h * 4 + i][2], sh1 = parb[h * 4 + i][3], sh2 = parb[h * 4 + i][4];
    const float gamma = parb[h * 4 + i][5];
    const float* prevw = (h ? prev_w_w : prev_w_r) + ((size_t)i * 512 + b) * 1024;

    float e4[4];
    float s = 0.f;
#pragma unroll
    for (int k = 0; k < 4; ++k) {
      const int u = th + 256 * k;
      const float z = beta * Abuf[u] / (sqrtf(nrm_s[u]) + EPS_);
      e4[k] = __expf(z);
      s += e4[k];
    }
#pragma unroll
    for (int off = 32; off > 0; off >>= 1) s += __shfl_xor(s, off);
    if (l == 0) redB[w] = s;
    __syncthreads();
    const float gsum = redB[h * 4] + redB[h * 4 + 1] + redB[h * 4 + 2] + redB[h * 4 + 3];
    const float invs = 1.f / gsum;
    float wg4[4];
#pragma unroll
    for (int k = 0; k < 4; ++k) {
      const int u = th + 256 * k;
      wg4[k] = g * (e4[k] * invs) + (1.f - g) * prevw[u];
      Abuf[u] = wg4[k];
    }
    __syncthreads();
    float wp4[4];
    float s2 = 0.f;
#pragma unroll
    for (int k = 0; k < 4; ++k) {
      const int u = th + 256 * k;
      const float ws = sh0 * Abuf[(u + 1023) & 1023] + sh1 * wg4[k] + sh2 * Abuf[(u + 1) & 1023];
      wp4[k] = (ws > 0.f) ? exp2f(gamma * __log2f(ws)) : 0.f;
      s2 += wp4[k];
    }
#pragma unroll
    for (int off = 32; off > 0; off >>= 1) s2 += __shfl_xor(s2, off);
    if (l == 0) redC[w] = s2;
    __syncthreads();
    const float gsum2 = redC[h * 4] + redC[h * 4 + 1] + redC[h * 4 + 2] + redC[h * 4 + 3];
    const float inv2 = 1.f / (gsum2 + EPS_);
#pragma unroll
    for (int k = 0; k < 4; ++k) Abuf[th + 256 * k] = wp4[k] * inv2;
    __syncthreads();  // final weights visible

    // ---- per-head e/a packed into registers (bf16)
    uint32x4_ epk0 = {}, epk1 = {}, apk0 = {}, apk1 = {};
    if (i < 3) {
      const f32x4 e0 = *(const f32x4*)&eb[i][q * 8];
      const f32x4 e1 = *(const f32x4*)&eb[i][q * 8 + 4];
      const f32x4 e2 = *(const f32x4*)&eb[i][32 + q * 8];
      const f32x4 e3 = *(const f32x4*)&eb[i][32 + q * 8 + 4];
      const f32x4 a0_ = *(const f32x4*)&ab[i][q * 8];
      const f32x4 a1_ = *(const f32x4*)&ab[i][q * 8 + 4];
      const f32x4 a2_ = *(const f32x4*)&ab[i][32 + q * 8];
      const f32x4 a3_ = *(const f32x4*)&ab[i][32 + q * 8 + 4];
      epk0[0] = cvtpk(e0[0], e0[1]); epk0[1] = cvtpk(e0[2], e0[3]);
      epk0[2] = cvtpk(e1[0], e1[1]); epk0[3] = cvtpk(e1[2], e1[3]);
      epk1[0] = cvtpk(e2[0], e2[1]); epk1[1] = cvtpk(e2[2], e2[3]);
      epk1[2] = cvtpk(e3[0], e3[1]); epk1[3] = cvtpk(e3[2], e3[3]);
      apk0[0] = cvtpk(a0_[0], a0_[1]); apk0[1] = cvtpk(a0_[2], a0_[3]);
      apk0[2] = cvtpk(a1_[0], a1_[1]); apk0[3] = cvtpk(a1_[2], a1_[3]);
      apk1[0] = cvtpk(a2_[0], a2_[1]); apk1[1] = cvtpk(a2_[2], a2_[3]);
      apk1[2] = cvtpk(a3_[0], a3_[1]); apk1[3] = cvtpk(a3_[2], a3_[3]);
    }

    // ---- sweep: read partials (pre-update v) + in-register update
    float r[16] = {0.f, 0.f, 0.f, 0.f, 0.f, 0.f, 0.f, 0.f,
                   0.f, 0.f, 0.f, 0.f, 0.f, 0.f, 0.f, 0.f};
#pragma unroll
    for (int tt = 0; tt < 8; ++tt) {
      const int row = (w * 8 + tt) * 16 + p;
      const float wr = Ar[row];
      const float ww = (i < 3) ? Aw[row] : 0.f;
#pragma unroll
      for (int wd = 0; wd < 4; ++wd) {
        const unsigned uv = va[tt][wd];
        const float v0 = bflo2f(uv), v1 = bfhi2f(uv);
        r[wd * 2 + 0] = fmaf(wr, v0, r[wd * 2 + 0]);
        r[wd * 2 + 1] = fmaf(wr, v1, r[wd * 2 + 1]);
        if (i < 3) {
          const unsigned ue = epk0[wd], ua = apk0[wd];
          const float n0 = fmaf(v0, fmaf(-ww, bflo2f(ue), 1.f), ww * bflo2f(ua));
          const float n1 = fmaf(v1, fmaf(-ww, bfhi2f(ue), 1.f), ww * bfhi2f(ua));
          va[tt][wd] = cvtpk(n0, n1);
        }
      }
#pragma unroll
      for (int wd = 0; wd < 4; ++wd) {
        const unsigned uv = vb[tt][wd];
        const float v0 = bflo2f(uv), v1 = bfhi2f(uv);
        r[8 + wd * 2 + 0] = fmaf(wr, v0, r[8 + wd * 2 + 0]);
        r[8 + wd * 2 + 1] = fmaf(wr, v1, r[8 + wd * 2 + 1]);
        if (i < 3) {
          const unsigned ue = epk1[wd], ua = apk1[wd];
          const float n0 = fmaf(v0, fmaf(-ww, bflo2f(ue), 1.f), ww * bflo2f(ua));
          const float n1 = fmaf(v1, fmaf(-ww, bfhi2f(ue), 1.f), ww * bfhi2f(ua));
          vb[tt][wd] = cvtpk(n0, n1);
        }
      }
    }

    // ---- fold 16 col-partials across the 16 lanes of each q-group
#pragma unroll
    for (int j = 0; j < 8; ++j) {
      const float send = (p & 1) ? r[j] : r[j + 8];
      r[j] = ((p & 1) ? r[j + 8] : r[j]) + __shfl_xor(send, 1);
    }
#pragma unroll
    for (int j = 0; j < 4; ++j) {
      const float send = (p & 2) ? r[j] : r[j + 4];
      r[j] = ((p & 2) ? r[j + 4] : r[j]) + __shfl_xor(send, 2);
    }
#pragma unroll
    for (int j = 0; j < 2; ++j) {
      const float send = (p & 4) ? r[j] : r[j + 2];
      r[j] = ((p & 4) ? r[j + 2] : r[j]) + __shfl_xor(send, 4);
    }
    {
      const float send = (p & 8) ? r[0] : r[1];
      r[0] = ((p & 8) ? r[1] : r[0]) + __shfl_xor(send, 8);
    }
    {
      const int idx = ((p & 1) << 3) | ((p & 2) << 1) | ((p & 4) >> 1) | ((p & 8) >> 3);
      const int col = (idx & 8) ? (32 + q * 8 + (idx & 7)) : (q * 8 + idx);
      racc[w][col] = r[0];
    }

    if (i < 3) score_pass(i + 1);  // next head's scores/norms from updated regs
    __syncthreads();               // racc + next scores visible

    if (t < 64) {
      float s3 = 0.f;
#pragma unroll
      for (int wv = 0; wv < 8; ++wv) s3 += racc[wv][t];
      Aoutb[(size_t)b * 768 + 512 + i * 64 + t] = (unsigned short)f2bf(s3);
    }
  }
}

extern "C" void kernel_launch(void* const* d_in, const int* in_sizes, int n_in,
                              void* d_out, int out_size, void* d_ws, size_t ws_size,
                              hipStream_t stream) {
  (void)in_sizes; (void)n_in; (void)out_size; (void)ws_size;
  const float* in_data = (const float*)d_in[0];
  const float* memory = (const float*)d_in[1];
  const float* prev_reads = (const float*)d_in[2];
  const float* prev_w_r = (const float*)d_in[3];
  const float* prev_w_w = (const float*)d_in[4];
  const float* h0 = (const float*)d_in[5];
  const float* c0 = (const float*)d_in[6];
  const float* W_ih = (const float*)d_in[7];
  const float* b_ih = (const float*)d_in[8];
  const float* W_hh = (const float*)d_in[9];
  const float* b_hh = (const float*)d_in[10];
  const float* W_rh = (const float*)d_in[11];
  const float* b_rh = (const float*)d_in[12];
  const float* W_wh = (const float*)d_in[13];
  const float* b_wh = (const float*)d_in[14];
  const float* W_out = (const float*)d_in[15];
  const float* b_out = (const float*)d_in[16];
  float* out = (float*)d_out;

  char* base = (char*)d_ws;
  auto alloc = [&](size_t bytes) -> char* {
    char* p = base; base += (bytes + 255) & ~(size_t)255; return p;
  };
  unsigned short* x2b   = (unsigned short*)alloc((size_t)512 * 1024 * 2);
  unsigned short* Wcatb = (unsigned short*)alloc((size_t)2048 * 1024 * 2);
  float* bcat           = (float*)alloc(2048 * 4);
  float* gates          = (float*)alloc((size_t)512 * 2048 * 4);
  unsigned short* W2b   = (unsigned short*)alloc((size_t)1072 * 512 * 2);
  float* bcat2          = (float*)alloc(1072 * 4);
  unsigned short* Woutb = (unsigned short*)alloc((size_t)256 * 768 * 2);
  float* P              = (float*)alloc((size_t)512 * 1072 * 4);
  unsigned short* Aoutb = (unsigned short*)alloc((size_t)512 * 768 * 2);

  k_prep<<<2048, 256, 0, stream>>>(in_data, prev_reads, h0, W_ih, W_hh, b_ih, b_hh,
                                   W_rh, W_wh, W_out, b_rh, b_wh,
                                   x2b, Wcatb, bcat, W2b, Woutb, bcat2);
  k_gemm_mfma<false><<<dim3(64, 16), 64, 0, stream>>>(x2b, 1024, Wcatb, bcat, gates, 2048, 1024, 2048);
  k_lstm<<<1024, 256, 0, stream>>>(gates, c0, Aoutb);
  k_gemm_mfma<false><<<dim3(34, 16), 64, 0, stream>>>(Aoutb, 768, W2b, bcat2, P, 1072, 512, 1072);
  k_mega<<<512, 512, 0, stream>>>(memory, P, prev_w_r, prev_w_w, Aoutb);
  k_gemm_mfma<true><<<dim3(8, 16), 64, 0, stream>>>(Aoutb, 768, Woutb, b_out, out, 256, 768, 256);
}

// Round 8
// 153.434 us; speedup vs baseline: 2.1084x; 2.1084x over previous
//
#include <hip/hip_runtime.h>
#include <cmath>

#define B_ 512
#define EPS_ 1e-8f

typedef __bf16 bf16x8 __attribute__((ext_vector_type(8)));
typedef float f32x4 __attribute__((ext_vector_type(4)));
typedef unsigned uint32x4_ __attribute__((ext_vector_type(4)));

__device__ __forceinline__ float sigmoidf_(float x) { return 1.f / (1.f + expf(-x)); }
__device__ __forceinline__ float softplusf_(float x) { return x > 20.f ? x : log1pf(expf(x)); }
__device__ __forceinline__ unsigned f2bf(float x) {
  union { float f; unsigned u; } v; v.f = x;
  unsigned r = v.u + 0x7FFF + ((v.u >> 16) & 1);
  return r >> 16;
}
__device__ __forceinline__ float bfhi2f(unsigned u) { return __uint_as_float(u & 0xffff0000u); }
__device__ __forceinline__ float bflo2f(unsigned u) { return __uint_as_float(u << 16); }
// packed f32->bf16 (RNE), lo = a, hi = b
__device__ __forceinline__ unsigned cvtpk(float a, float b) {
  unsigned r;
  asm("v_cvt_pk_bf16_f32 %0, %1, %2" : "=v"(r) : "v"(a), "v"(b));
  return r;
}

// ---------------- one prep kernel: x2b + all weight conversions (grid-stride)
__global__ void k_prep(const float* __restrict__ in_data, const float* __restrict__ prev_reads,
                       const float* __restrict__ h0,
                       const float* __restrict__ W_ih, const float* __restrict__ W_hh,
                       const float* __restrict__ b_ih, const float* __restrict__ b_hh,
                       const float* __restrict__ W_rh, const float* __restrict__ W_wh,
                       const float* __restrict__ W_out,
                       const float* __restrict__ b_rh, const float* __restrict__ b_wh,
                       unsigned short* __restrict__ x2b,
                       unsigned short* __restrict__ Wcatb, float* __restrict__ bcat,
                       unsigned short* __restrict__ W2b, unsigned short* __restrict__ Woutb,
                       float* __restrict__ bcat2) {
  const int stride = gridDim.x * blockDim.x;
  const int t0 = blockIdx.x * blockDim.x + threadIdx.x;
  for (int i = t0; i < 512 * 1024; i += stride) {
    const int b = i >> 10, j = i & 1023;
    float v;
    if (j < 256) v = in_data[(size_t)b * 256 + j];
    else if (j < 512) { const int jj = j - 256; v = prev_reads[(size_t)(jj >> 6) * B_ * 64 + (size_t)b * 64 + (jj & 63)]; }
    else v = h0[(size_t)b * 512 + (j - 512)];
    x2b[i] = (unsigned short)f2bf(v);
  }
  for (int i = t0; i < 2048 * 1024; i += stride) {
    const int j = i >> 10, k = i & 1023;
    Wcatb[i] = (unsigned short)f2bf(k < 512 ? W_ih[(size_t)j * 512 + k] : W_hh[(size_t)j * 512 + (k - 512)]);
  }
  for (int i = t0; i < 2048; i += stride) bcat[i] = b_ih[i] + b_hh[i];
  for (int i = t0; i < 143360; i += stride) W2b[i] = (unsigned short)f2bf(W_rh[i]);
  for (int i = t0; i < 405504; i += stride) W2b[143360 + i] = (unsigned short)f2bf(W_wh[i]);
  for (int i = t0; i < 196608; i += stride) Woutb[i] = (unsigned short)f2bf(W_out[i]);
  for (int i = t0; i < 280; i += stride) bcat2[i] = b_rh[i];
  for (int i = t0; i < 792; i += stride) bcat2[280 + i] = b_wh[i];
}

// ---------------- bf16 MFMA GEMM, one wave per 32x32 tile, direct-from-global frags
template <bool SIG>
__global__ __launch_bounds__(64) void k_gemm_mfma(const unsigned short* __restrict__ A, int lda,
                                                  const unsigned short* __restrict__ W,
                                                  const float* __restrict__ bias,
                                                  float* __restrict__ C,
                                                  int Nn, int Kk, int ldc) {
  const int l = threadIdx.x;
  const int m0 = blockIdx.y * 32, n0 = blockIdx.x * 32;
  const int lr = l & 15, lk = (l >> 4) * 8;
  f32x4 acc00 = {0.f, 0.f, 0.f, 0.f}, acc01 = acc00, acc10 = acc00, acc11 = acc00;
  const size_t pa0 = (size_t)(m0 + lr) * lda + lk;
  const size_t pa1 = pa0 + (size_t)16 * lda;
  const bool bok0 = (n0 + lr) < Nn, bok1 = (n0 + 16 + lr) < Nn;
  const size_t pb0 = (size_t)(n0 + lr) * Kk + lk;
  const size_t pb1 = pb0 + (size_t)16 * Kk;
#pragma unroll 4
  for (int k0 = 0; k0 < Kk; k0 += 32) {
    bf16x8 a0 = *(const bf16x8*)(A + pa0 + k0);
    bf16x8 a1 = *(const bf16x8*)(A + pa1 + k0);
    bf16x8 b0 = {}, b1 = {};
    if (bok0) b0 = *(const bf16x8*)(W + pb0 + k0);
    if (bok1) b1 = *(const bf16x8*)(W + pb1 + k0);
    acc00 = __builtin_amdgcn_mfma_f32_16x16x32_bf16(a0, b0, acc00, 0, 0, 0);
    acc01 = __builtin_amdgcn_mfma_f32_16x16x32_bf16(a0, b1, acc01, 0, 0, 0);
    acc10 = __builtin_amdgcn_mfma_f32_16x16x32_bf16(a1, b0, acc10, 0, 0, 0);
    acc11 = __builtin_amdgcn_mfma_f32_16x16x32_bf16(a1, b1, acc11, 0, 0, 0);
  }
  const int orow = (l >> 4) * 4;
  f32x4 accs[2][2] = {{acc00, acc01}, {acc10, acc11}};
#pragma unroll
  for (int mi = 0; mi < 2; ++mi) {
#pragma unroll
    for (int nj = 0; nj < 2; ++nj) {
      const int n = n0 + nj * 16 + lr;
      if (n < Nn) {
        const float bv = bias[n];
#pragma unroll
        for (int r = 0; r < 4; ++r) {
          const int m = m0 + mi * 16 + orow + r;
          float v = accs[mi][nj][r] + bv;
          if (SIG) v = 1.f / (1.f + expf(-v));
          C[(size_t)m * ldc + n] = v;
        }
      }
    }
  }
}

// ---------------- LSTM pointwise -> h (bf16) into Aoutb rows (stride 768)
__global__ void k_lstm(const float* __restrict__ gates, const float* __restrict__ c0,
                       unsigned short* __restrict__ Aoutb) {
  const int idx = blockIdx.x * blockDim.x + threadIdx.x;  // < 512*512
  const int b = idx >> 9, j = idx & 511;
  const float* g = gates + (size_t)b * 2048;
  const float ig = g[j], fg = g[512 + j], gg = g[1024 + j], og = g[1536 + j];
  const float c = sigmoidf_(fg) * c0[idx] + sigmoidf_(ig) * tanhf(gg);
  Aoutb[(size_t)b * 768 + j] = (unsigned short)f2bf(sigmoidf_(og) * tanhf(c));
}

// ---------------- fused NTM head loop: one 512-thread block per batch row.
// Memory image lives in REGISTERS in MFMA A-frag layout (8 tiles/wave, 2 frags):
// lane holds row = tile*16 + (l&15), cols (l>>4)*8.. (a) and 32+(l>>4)*8.. (b).
// Scores/norms via MFMA from regs; update in-register; reads via per-lane fma
// partials + shuffle fold. LDS ~19 KB; launch_bounds (512,2) -> 128-VGPR cap,
// 2 blocks/CU co-resident. (512,4) capped VGPR at 64 and spilled the image
// to scratch: 1 GB/dispatch scratch traffic, 2.5x regression — do not lower.
__global__ __launch_bounds__(512, 2) void k_mega(const float* __restrict__ mem0,
                                                 const float* __restrict__ P,
                                                 const float* __restrict__ prev_w_r,
                                                 const float* __restrict__ prev_w_w,
                                                 unsigned short* __restrict__ Aoutb) {
  const int b = blockIdx.x;
  const int t = threadIdx.x;   // 512
  const int l = t & 63;
  const int w = t >> 6;        // wave 0..7
  const int p = l & 15;        // frag row within tile
  const int q = l >> 4;        // k-chunk

  __shared__ float Ar[1024], Aw[1024], nrm_s[1024];
  __shared__ float racc[8][64];
  __shared__ float knb[8][64];
  __shared__ float parb[8][8];
  __shared__ float eb[4][64], ab[4][64];
  __shared__ float redB[8], redC[8];

  // ---- stage memory rows into register fragments (f32 global -> packed bf16)
  uint32x4_ va[8], vb[8];
  {
    const float* src = mem0 + (size_t)b * 65536;
#pragma unroll
    for (int tt = 0; tt < 8; ++tt) {
      const float* rp = src + ((w * 8 + tt) * 16 + p) * 64;
      const float4 f0 = *(const float4*)(rp + q * 8);
      const float4 f1 = *(const float4*)(rp + q * 8 + 4);
      const float4 f2 = *(const float4*)(rp + 32 + q * 8);
      const float4 f3 = *(const float4*)(rp + 32 + q * 8 + 4);
      va[tt][0] = cvtpk(f0.x, f0.y); va[tt][1] = cvtpk(f0.z, f0.w);
      va[tt][2] = cvtpk(f1.x, f1.y); va[tt][3] = cvtpk(f1.z, f1.w);
      vb[tt][0] = cvtpk(f2.x, f2.y); vb[tt][1] = cvtpk(f2.z, f2.w);
      vb[tt][2] = cvtpk(f3.x, f3.y); vb[tt][3] = cvtpk(f3.z, f3.w);
    }
  }

  // ---- params phase (each wave = one unit: type = w>>2, head = w&3)
  {
    const int type = w >> 2, head = w & 3;
    const float* pp = P + (size_t)b * 1072 + (type == 0 ? head * 70 : 280 + head * 198);
    const float kv = tanhf(pp[l]);
    float ss = kv * kv;
#pragma unroll
    for (int off = 32; off > 0; off >>= 1) ss += __shfl_xor(ss, off);
    knb[w][l] = kv / (sqrtf(ss) + EPS_);
    if (l == 0) {
      parb[w][0] = softplusf_(pp[64]);
      parb[w][1] = sigmoidf_(pp[65]);
      const float s0 = pp[66], s1 = pp[67], s2 = pp[68];
      const float mx = fmaxf(s0, fmaxf(s1, s2));
      const float e0 = expf(s0 - mx), e1 = expf(s1 - mx), e2 = expf(s2 - mx);
      const float inv = 1.f / (e0 + e1 + e2);
      parb[w][2] = e0 * inv; parb[w][3] = e1 * inv; parb[w][4] = e2 * inv;
      parb[w][5] = 1.f + softplusf_(pp[69]);
    }
    if (type == 1) {
      eb[head][l] = sigmoidf_(pp[70 + l]);
      ab[head][l] = tanhf(pp[134 + l]);
    }
  }
  __syncthreads();

  // ---- key B-fragments (cols 0..3 read keys, 4..7 write keys, 8..15 zero)
  bf16x8 kb0 = {}, kb1 = {};
  {
    const int c = l & 15, ks = (l >> 4) * 8;
    if (c < 8) {
#pragma unroll
      for (int j = 0; j < 8; ++j) {
        kb0[j] = (__bf16)knb[c][ks + j];
        kb1[j] = (__bf16)knb[c][32 + ks + j];
      }
    }
  }

  // ---- MFMA score pass from registers: scores for head hj + Gram-diag norms
  auto score_pass = [&](int hj) {
#pragma unroll
    for (int tt = 0; tt < 8; ++tt) {
      const int tile = w * 8 + tt;
      const bf16x8 a0 = __builtin_bit_cast(bf16x8, va[tt]);
      const bf16x8 a1 = __builtin_bit_cast(bf16x8, vb[tt]);
      f32x4 sacc = {0.f, 0.f, 0.f, 0.f}, gacc = {0.f, 0.f, 0.f, 0.f};
      sacc = __builtin_amdgcn_mfma_f32_16x16x32_bf16(a0, kb0, sacc, 0, 0, 0);
      sacc = __builtin_amdgcn_mfma_f32_16x16x32_bf16(a1, kb1, sacc, 0, 0, 0);
      gacc = __builtin_amdgcn_mfma_f32_16x16x32_bf16(a0, a0, gacc, 0, 0, 0);
      gacc = __builtin_amdgcn_mfma_f32_16x16x32_bf16(a1, a1, gacc, 0, 0, 0);
      if (p == hj)        *(f32x4*)&Ar[tile * 16 + q * 4] = sacc;
      if (p == 4 + hj)    *(f32x4*)&Aw[tile * 16 + q * 4] = sacc;
      if ((p >> 2) == q)  nrm_s[tile * 16 + p] = gacc[p & 3];
    }
  };

  score_pass(0);
  __syncthreads();  // scores + norms ready for head 0

  const int h = w >> 2;      // 0: read-type half (waves 0-3), 1: write-type half
  const int th = t & 255;
  float* Abuf = h ? Aw : Ar;

  for (int i = 0; i < 4; ++i) {
    // ---- finalize: cosine-normalize + softmax (no max-sub; beta<=~2) + gate + shift + sharpen
    const float beta = parb[h * 4 + i][0], g = parb[h * 4 + i][1];
    const float sh0 = parb[h * 4 + i][2], sh1 = parb[h * 4 + i][3], sh2 = parb[h * 4 + i][4];
    const float gamma = parb[h * 4 + i][5];
    const float* prevw = (h ? prev_w_w : prev_w_r) + ((size_t)i * 512 + b) * 1024;

    float e4[4];
    float s = 0.f;
#pragma unroll
    for (int k = 0; k < 4; ++k) {
      const int u = th + 256 * k;
      const float z = beta * Abuf[u] / (sqrtf(nrm_s[u]) + EPS_);
      e4[k] = __expf(z);
      s += e4[k];
    }
#pragma unroll
    for (int off = 32; off > 0; off >>= 1) s += __shfl_xor(s, off);
    if (l == 0) redB[w] = s;
    __syncthreads();
    const float gsum = redB[h * 4] + redB[h * 4 + 1] + redB[h * 4 + 2] + redB[h * 4 + 3];
    const float invs = 1.f / gsum;
    float wg4[4];
#pragma unroll
    for (int k = 0; k < 4; ++k) {
      const int u = th + 256 * k;
      wg4[k] = g * (e4[k] * invs) + (1.f - g) * prevw[u];
      Abuf[u] = wg4[k];
    }
    __syncthreads();
    float wp4[4];
    float s2 = 0.f;
#pragma unroll
    for (int k = 0; k < 4; ++k) {
      const int u = th + 256 * k;
      const float ws = sh0 * Abuf[(u + 1023) & 1023] + sh1 * wg4[k] + sh2 * Abuf[(u + 1) & 1023];
      wp4[k] = (ws > 0.f) ? exp2f(gamma * __log2f(ws)) : 0.f;
      s2 += wp4[k];
    }
#pragma unroll
    for (int off = 32; off > 0; off >>= 1) s2 += __shfl_xor(s2, off);
    if (l == 0) redC[w] = s2;
    __syncthreads();
    const float gsum2 = redC[h * 4] + redC[h * 4 + 1] + redC[h * 4 + 2] + redC[h * 4 + 3];
    const float inv2 = 1.f / (gsum2 + EPS_);
#pragma unroll
    for (int k = 0; k < 4; ++k) Abuf[th + 256 * k] = wp4[k] * inv2;
    __syncthreads();  // final weights visible

    // ---- per-head e/a packed into registers (bf16)
    uint32x4_ epk0 = {}, epk1 = {}, apk0 = {}, apk1 = {};
    if (i < 3) {
      const f32x4 e0 = *(const f32x4*)&eb[i][q * 8];
      const f32x4 e1 = *(const f32x4*)&eb[i][q * 8 + 4];
      const f32x4 e2 = *(const f32x4*)&eb[i][32 + q * 8];
      const f32x4 e3 = *(const f32x4*)&eb[i][32 + q * 8 + 4];
      const f32x4 a0_ = *(const f32x4*)&ab[i][q * 8];
      const f32x4 a1_ = *(const f32x4*)&ab[i][q * 8 + 4];
      const f32x4 a2_ = *(const f32x4*)&ab[i][32 + q * 8];
      const f32x4 a3_ = *(const f32x4*)&ab[i][32 + q * 8 + 4];
      epk0[0] = cvtpk(e0[0], e0[1]); epk0[1] = cvtpk(e0[2], e0[3]);
      epk0[2] = cvtpk(e1[0], e1[1]); epk0[3] = cvtpk(e1[2], e1[3]);
      epk1[0] = cvtpk(e2[0], e2[1]); epk1[1] = cvtpk(e2[2], e2[3]);
      epk1[2] = cvtpk(e3[0], e3[1]); epk1[3] = cvtpk(e3[2], e3[3]);
      apk0[0] = cvtpk(a0_[0], a0_[1]); apk0[1] = cvtpk(a0_[2], a0_[3]);
      apk0[2] = cvtpk(a1_[0], a1_[1]); apk0[3] = cvtpk(a1_[2], a1_[3]);
      apk1[0] = cvtpk(a2_[0], a2_[1]); apk1[1] = cvtpk(a2_[2], a2_[3]);
      apk1[2] = cvtpk(a3_[0], a3_[1]); apk1[3] = cvtpk(a3_[2], a3_[3]);
    }

    // ---- sweep: read partials (pre-update v) + in-register update
    float r[16] = {0.f, 0.f, 0.f, 0.f, 0.f, 0.f, 0.f, 0.f,
                   0.f, 0.f, 0.f, 0.f, 0.f, 0.f, 0.f, 0.f};
#pragma unroll
    for (int tt = 0; tt < 8; ++tt) {
      const int row = (w * 8 + tt) * 16 + p;
      const float wr = Ar[row];
      const float ww = (i < 3) ? Aw[row] : 0.f;
#pragma unroll
      for (int wd = 0; wd < 4; ++wd) {
        const unsigned uv = va[tt][wd];
        const float v0 = bflo2f(uv), v1 = bfhi2f(uv);
        r[wd * 2 + 0] = fmaf(wr, v0, r[wd * 2 + 0]);
        r[wd * 2 + 1] = fmaf(wr, v1, r[wd * 2 + 1]);
        if (i < 3) {
          const unsigned ue = epk0[wd], ua = apk0[wd];
          const float n0 = fmaf(v0, fmaf(-ww, bflo2f(ue), 1.f), ww * bflo2f(ua));
          const float n1 = fmaf(v1, fmaf(-ww, bfhi2f(ue), 1.f), ww * bfhi2f(ua));
          va[tt][wd] = cvtpk(n0, n1);
        }
      }
#pragma unroll
      for (int wd = 0; wd < 4; ++wd) {
        const unsigned uv = vb[tt][wd];
        const float v0 = bflo2f(uv), v1 = bfhi2f(uv);
        r[8 + wd * 2 + 0] = fmaf(wr, v0, r[8 + wd * 2 + 0]);
        r[8 + wd * 2 + 1] = fmaf(wr, v1, r[8 + wd * 2 + 1]);
        if (i < 3) {
          const unsigned ue = epk1[wd], ua = apk1[wd];
          const float n0 = fmaf(v0, fmaf(-ww, bflo2f(ue), 1.f), ww * bflo2f(ua));
          const float n1 = fmaf(v1, fmaf(-ww, bfhi2f(ue), 1.f), ww * bfhi2f(ua));
          vb[tt][wd] = cvtpk(n0, n1);
        }
      }
    }

    // ---- fold 16 col-partials across the 16 lanes of each q-group
#pragma unroll
    for (int j = 0; j < 8; ++j) {
      const float send = (p & 1) ? r[j] : r[j + 8];
      r[j] = ((p & 1) ? r[j + 8] : r[j]) + __shfl_xor(send, 1);
    }
#pragma unroll
    for (int j = 0; j < 4; ++j) {
      const float send = (p & 2) ? r[j] : r[j + 4];
      r[j] = ((p & 2) ? r[j + 4] : r[j]) + __shfl_xor(send, 2);
    }
#pragma unroll
    for (int j = 0; j < 2; ++j) {
      const float send = (p & 4) ? r[j] : r[j + 2];
      r[j] = ((p & 4) ? r[j + 2] : r[j]) + __shfl_xor(send, 4);
    }
    {
      const float send = (p & 8) ? r[0] : r[1];
      r[0] = ((p & 8) ? r[1] : r[0]) + __shfl_xor(send, 8);
    }
    {
      const int idx = ((p & 1) << 3) | ((p & 2) << 1) | ((p & 4) >> 1) | ((p & 8) >> 3);
      const int col = (idx & 8) ? (32 + q * 8 + (idx & 7)) : (q * 8 + idx);
      racc[w][col] = r[0];
    }

    if (i < 3) score_pass(i + 1);  // next head's scores/norms from updated regs
    __syncthreads();               // racc + next scores visible

    if (t < 64) {
      float s3 = 0.f;
#pragma unroll
      for (int wv = 0; wv < 8; ++wv) s3 += racc[wv][t];
      Aoutb[(size_t)b * 768 + 512 + i * 64 + t] = (unsigned short)f2bf(s3);
    }
  }
}

extern "C" void kernel_launch(void* const* d_in, const int* in_sizes, int n_in,
                              void* d_out, int out_size, void* d_ws, size_t ws_size,
                              hipStream_t stream) {
  (void)in_sizes; (void)n_in; (void)out_size; (void)ws_size;
  const float* in_data = (const float*)d_in[0];
  const float* memory = (const float*)d_in[1];
  const float* prev_reads = (const float*)d_in[2];
  const float* prev_w_r = (const float*)d_in[3];
  const float* prev_w_w = (const float*)d_in[4];
  const float* h0 = (const float*)d_in[5];
  const float* c0 = (const float*)d_in[6];
  const float* W_ih = (const float*)d_in[7];
  const float* b_ih = (const float*)d_in[8];
  const float* W_hh = (const float*)d_in[9];
  const float* b_hh = (const float*)d_in[10];
  const float* W_rh = (const float*)d_in[11];
  const float* b_rh = (const float*)d_in[12];
  const float* W_wh = (const float*)d_in[13];
  const float* b_wh = (const float*)d_in[14];
  const float* W_out = (const float*)d_in[15];
  const float* b_out = (const float*)d_in[16];
  float* out = (float*)d_out;

  char* base = (char*)d_ws;
  auto alloc = [&](size_t bytes) -> char* {
    char* p = base; base += (bytes + 255) & ~(size_t)255; return p;
  };
  unsigned short* x2b   = (unsigned short*)alloc((size_t)512 * 1024 * 2);
  unsigned short* Wcatb = (unsigned short*)alloc((size_t)2048 * 1024 * 2);
  float* bcat           = (float*)alloc(2048 * 4);
  float* gates          = (float*)alloc((size_t)512 * 2048 * 4);
  unsigned short* W2b   = (unsigned short*)alloc((size_t)1072 * 512 * 2);
  float* bcat2          = (float*)alloc(1072 * 4);
  unsigned short* Woutb = (unsigned short*)alloc((size_t)256 * 768 * 2);
  float* P              = (float*)alloc((size_t)512 * 1072 * 4);
  unsigned short* Aoutb = (unsigned short*)alloc((size_t)512 * 768 * 2);

  k_prep<<<2048, 256, 0, stream>>>(in_data, prev_reads, h0, W_ih, W_hh, b_ih, b_hh,
                                   W_rh, W_wh, W_out, b_rh, b_wh,
                                   x2b, Wcatb, bcat, W2b, Woutb, bcat2);
  k_gemm_mfma<false><<<dim3(64, 16), 64, 0, stream>>>(x2b, 1024, Wcatb, bcat, gates, 2048, 1024, 2048);
  k_lstm<<<1024, 256, 0, stream>>>(gates, c0, Aoutb);
  k_gemm_mfma<false><<<dim3(34, 16), 64, 0, stream>>>(Aoutb, 768, W2b, bcat2, P, 1072, 512, 1072);
  k_mega<<<512, 512, 0, stream>>>(memory, P, prev_w_r, prev_w_w, Aoutb);
  k_gemm_mfma<true><<<dim3(8, 16), 64, 0, stream>>>(Aoutb, 768, Woutb, b_out, out, 256, 768, 256);
}